// Round 21
// baseline (444.600 us; speedup 1.0000x reference)
//
#include <hip/hip_runtime.h>
#include <hip/hip_bf16.h>

// MHSA: B=16, C=256, H=W=48, N=2304.
// S[b,n,m] = q[b,:,n]·k[b,:,m] + rhq[b][n%48][m] + rwq[b][n/48][m]
// att = softmax_m(S); out[b,c,n] = sum_m v[b,c,m] att[n,m]
// Numerics: attn S q 1-pass f16, defer-max THR=8 (R17/18-proven, 0.0625).
// R21: (1) s_setprio(1) around attn MFMA clusters (guide T5: +4-7% attn when
// waves phase-diverse — ours are, 2 async blocks/CU). (2) nsplit 4->6:
// tail waste 11%->4% (1728 blocks, 6.75 rounds/CU); runtime fallback 6->4->2.

#define BB 16
#define CC 256
#define HH 48
#define NN 2304

typedef float f32x4 __attribute__((ext_vector_type(4)));
typedef short bf16x8 __attribute__((ext_vector_type(8)));
typedef _Float16 f16x8 __attribute__((ext_vector_type(8)));

#define MFMA(a, b, c)  __builtin_amdgcn_mfma_f32_16x16x32_bf16((a), (b), (c), 0, 0, 0)
#define MFMAH(a, b, c) __builtin_amdgcn_mfma_f32_16x16x32_f16((a), (b), (c), 0, 0, 0)

__device__ inline bf16x8 ldg8(const __hip_bfloat16* p) {
    return *reinterpret_cast<const bf16x8*>(p);
}
__device__ inline f16x8 ldh8(const _Float16* p) {
    return *reinterpret_cast<const f16x8*>(p);
}
__device__ inline float bf2f(unsigned short v) {
    unsigned u = (unsigned)v << 16;
    float f;
    __builtin_memcpy(&f, &u, 4);
    return f;
}

typedef __attribute__((address_space(3))) unsigned int lds_uint;
typedef const __attribute__((address_space(1))) unsigned int gbl_uint;

__device__ inline void gload_lds16(const void* g, void* l) {
    __builtin_amdgcn_global_load_lds((gbl_uint*)g, (lds_uint*)l, 16, 0, 0);
}

// ---- prep: W -> single f16 plane ([3][256][256]) ----
__global__ __launch_bounds__(256) void k_prep_w(const float* __restrict__ Wq,
        const float* __restrict__ Wk, const float* __restrict__ Wv,
        _Float16* __restrict__ w) {
    int i = blockIdx.x * 256 + threadIdx.x;         // < 3*65536
    int m = i >> 16, j = i & 65535;
    const float* W = (m == 0) ? Wq : ((m == 1) ? Wk : Wv);
    w[i] = (_Float16)W[j];
}

// ---- prep: relhT[h][c] = rel_h[c][h] etc, f16 ----
__global__ __launch_bounds__(256) void k_prep_rel(const float* __restrict__ rel_h,
        const float* __restrict__ rel_w,
        _Float16* __restrict__ relhT, _Float16* __restrict__ relwT) {
    int i = blockIdx.x * 256 + threadIdx.x;         // < 48*256
    int h = i >> 8, c = i & 255;
    relhT[i] = (_Float16)rel_h[c * HH + h];
    relwT[i] = (_Float16)rel_w[c * HH + h];
}

// ---- unified QKV projection + fused pos rank-split (R20) ----
__global__ __launch_bounds__(256) void k_projqkv(
        const float* __restrict__ x,
        const _Float16* __restrict__ w,
        const float* __restrict__ bq, const float* __restrict__ bk, const float* __restrict__ bv,
        const _Float16* __restrict__ relhT, const _Float16* __restrict__ relwT,
        _Float16* __restrict__ qt_hi, _Float16* __restrict__ kt,
        __hip_bfloat16* __restrict__ vbuf,
        float* __restrict__ rhq, float* __restrict__ rwq) {
    __shared__ float xf[32][257];                          // 32.9KB; reused: qlds, v-repack
    __shared__ __align__(16) _Float16 lds_a[2][32][256];   // [hi/lo][row][c] 32KB swizzled
    _Float16* qlds = reinterpret_cast<_Float16*>(&xf[0][0]);        // [2][32][256] swizzled
    __hip_bfloat16* vt = reinterpret_cast<__hip_bfloat16*>(&xf[0][0]); // [256][40] padded
    int b = blockIdx.y;
    int n0 = blockIdx.x * 32;
    int t = threadIdx.x;
    int wave = t >> 6, lane = t & 63;
    int lr = lane & 15, lg = lane >> 4;
    int o0 = wave * 64;
    const size_t bN = (size_t)b * NN;

    {
        int nj = t & 31, cg = t >> 5;
        #pragma unroll
        for (int it = 0; it < 32; ++it) {
            int c = it * 8 + cg;
            xf[nj][c] = x[((size_t)b * CC + c) * NN + n0 + nj];
        }
    }
    __syncthreads();
    {
        int r = t & 31, cg = t >> 5;
        #pragma unroll
        for (int i = 0; i < 32; ++i) {
            int c = cg + 8 * i;
            float v = xf[r][c];
            _Float16 h = (_Float16)v;
            int pc = (((c >> 3) ^ (r & 7)) << 3) | (c & 7);
            lds_a[0][r][pc] = h;
            lds_a[1][r][pc] = (_Float16)(v - (float)h);
        }
    }
    __syncthreads();   // xf reads complete -> safe to overwrite as qlds

    // ---- q-GEMM (2-pass) ----
    {
        const _Float16* wp = w;
        f32x4 acc[2][4] = {};
        #pragma unroll
        for (int ks = 0; ks < 8; ++ks) {
            int kk = ks * 32 + lg * 8;
            f16x8 ah[2], al[2];
            #pragma unroll
            for (int nt = 0; nt < 2; ++nt) {
                int row = nt * 16 + lr;
                int ch = ((ks * 4 + lg) ^ (lr & 7)) * 8;
                ah[nt] = *reinterpret_cast<const f16x8*>(&lds_a[0][row][ch]);
                al[nt] = *reinterpret_cast<const f16x8*>(&lds_a[1][row][ch]);
            }
            #pragma unroll
            for (int ot = 0; ot < 4; ++ot) {
                int rowB = o0 + ot * 16 + lr;
                f16x8 bh = ldh8(wp + rowB * CC + kk);
                #pragma unroll
                for (int nt = 0; nt < 2; ++nt) {
                    acc[nt][ot] = MFMAH(ah[nt], bh, acc[nt][ot]);
                    acc[nt][ot] = MFMAH(al[nt], bh, acc[nt][ot]);
                }
            }
        }
        #pragma unroll
        for (int ot = 0; ot < 4; ++ot) {
            int o = o0 + ot * 16 + lr;
            float bb = bq[o];
            #pragma unroll
            for (int nt = 0; nt < 2; ++nt) {
                #pragma unroll
                for (int r = 0; r < 4; ++r) {
                    int nl = nt * 16 + lg * 4 + r;
                    float y = acc[nt][ot][r] + bb;
                    _Float16 h = (_Float16)y;
                    _Float16 lo = (_Float16)(y - (float)h);
                    qt_hi[(bN + n0 + nl) * CC + o] = h;
                    int pc = (((o >> 3) ^ (nl & 7)) << 3) | (o & 7);
                    qlds[nl * 256 + pc] = h;
                    qlds[8192 + nl * 256 + pc] = lo;
                }
            }
        }
    }
    __syncthreads();   // qlds complete

    // ---- fused pos rank-split (bit-identical to old k_posq) ----
    {
        int rel_sel = wave >> 1, mtile = wave & 1;
        const _Float16* rel = rel_sel ? relwT : relhT;
        float* rout = rel_sel ? rwq : rhq;
        int brow = mtile * 16 + lr;
        f32x4 pacc[3] = {};
        #pragma unroll
        for (int ks = 0; ks < 8; ++ks) {
            int kk = ks * 32 + lg * 8;
            int bch = ((ks * 4 + lg) ^ (brow & 7)) * 8;
            f16x8 bh = *reinterpret_cast<const f16x8*>(&qlds[brow * 256 + bch]);
            f16x8 bl = *reinterpret_cast<const f16x8*>(&qlds[8192 + brow * 256 + bch]);
            #pragma unroll
            for (int ht = 0; ht < 3; ++ht) {
                f16x8 a = ldh8(rel + (ht * 16 + lr) * CC + kk);
                pacc[ht] = MFMAH(a, bh, pacc[ht]);
                pacc[ht] = MFMAH(a, bl, pacc[ht]);
            }
        }
        #pragma unroll
        for (int ht = 0; ht < 3; ++ht) {
            #pragma unroll
            for (int r = 0; r < 4; ++r) {
                int h = ht * 16 + lg * 4 + r;
                int m = n0 + mtile * 16 + lr;
                rout[((size_t)b * HH + h) * NN + m] = pacc[ht][r];
            }
        }
    }

    // ---- k-GEMM (2-pass) ----
    {
        const _Float16* wp = w + 65536;
        f32x4 acc[2][4] = {};
        #pragma unroll
        for (int ks = 0; ks < 8; ++ks) {
            int kk = ks * 32 + lg * 8;
            f16x8 ah[2], al[2];
            #pragma unroll
            for (int nt = 0; nt < 2; ++nt) {
                int row = nt * 16 + lr;
                int ch = ((ks * 4 + lg) ^ (lr & 7)) * 8;
                ah[nt] = *reinterpret_cast<const f16x8*>(&lds_a[0][row][ch]);
                al[nt] = *reinterpret_cast<const f16x8*>(&lds_a[1][row][ch]);
            }
            #pragma unroll
            for (int ot = 0; ot < 4; ++ot) {
                int rowB = o0 + ot * 16 + lr;
                f16x8 bh = ldh8(wp + rowB * CC + kk);
                #pragma unroll
                for (int nt = 0; nt < 2; ++nt) {
                    acc[nt][ot] = MFMAH(ah[nt], bh, acc[nt][ot]);
                    acc[nt][ot] = MFMAH(al[nt], bh, acc[nt][ot]);
                }
            }
        }
        #pragma unroll
        for (int ot = 0; ot < 4; ++ot) {
            int o = o0 + ot * 16 + lr;
            float bb = bk[o];
            #pragma unroll
            for (int nt = 0; nt < 2; ++nt) {
                #pragma unroll
                for (int r = 0; r < 4; ++r) {
                    int nl = nt * 16 + lg * 4 + r;
                    kt[(bN + n0 + nl) * CC + o] = (_Float16)(acc[nt][ot][r] + bb);
                }
            }
        }
    }

    // ---- v-GEMM (1-pass) + full-line store via LDS repack ----
    {
        const _Float16* wp = w + 2 * 65536;
        f32x4 acc[2][4] = {};
        #pragma unroll
        for (int ks = 0; ks < 8; ++ks) {
            int kk = ks * 32 + lg * 8;
            f16x8 ah[2];
            #pragma unroll
            for (int nt = 0; nt < 2; ++nt) {
                int row = nt * 16 + lr;
                int ch = ((ks * 4 + lg) ^ (lr & 7)) * 8;
                ah[nt] = *reinterpret_cast<const f16x8*>(&lds_a[0][row][ch]);
            }
            #pragma unroll
            for (int ot = 0; ot < 4; ++ot) {
                int rowB = o0 + ot * 16 + lr;
                f16x8 bh = ldh8(wp + rowB * CC + kk);
                #pragma unroll
                for (int nt = 0; nt < 2; ++nt)
                    acc[nt][ot] = MFMAH(ah[nt], bh, acc[nt][ot]);
            }
        }
        __syncthreads();   // all waves past pos-phase reads of qlds (xf reuse)
        #pragma unroll
        for (int ot = 0; ot < 4; ++ot) {
            int o = o0 + ot * 16 + lr;
            float bb = bv[o];
            #pragma unroll
            for (int nt = 0; nt < 2; ++nt) {
                #pragma unroll
                for (int r = 0; r < 4; ++r) {
                    int nl = nt * 16 + lg * 4 + r;
                    vt[o * 40 + nl] = __float2bfloat16(acc[nt][ot][r] + bb);
                }
            }
        }
        __syncthreads();
        #pragma unroll
        for (int j = 0; j < 4; ++j) {
            bf16x8 vv = *reinterpret_cast<const bf16x8*>(&vt[t * 40 + j * 8]);
            *reinterpret_cast<bf16x8*>(&vbuf[((size_t)b * CC + t) * NN + n0 + j * 8]) = vv;
        }
    }
}

// ---- flash attention, split-KV, setprio'd MFMA clusters (R21) ----
__global__ __launch_bounds__(512, 2) void k_attn(
        const _Float16* __restrict__ qt_hi,
        const _Float16* __restrict__ kt,
        const float* __restrict__ rhq, const float* __restrict__ rwq,
        const __hip_bfloat16* __restrict__ vbuf,
        __hip_bfloat16* __restrict__ o0, __hip_bfloat16* __restrict__ o1,
        __hip_bfloat16* __restrict__ o2, __hip_bfloat16* __restrict__ o3,
        __hip_bfloat16* __restrict__ o4, __hip_bfloat16* __restrict__ o5,
        float2* __restrict__ ml, int tpb) {
    __shared__ __align__(16) _Float16 lds_k[2][64][128];          // [slice][row][k] 32KB
    __shared__ __align__(16) __hip_bfloat16 lds_v[256][64];       // [c][m] 32KB (swizzled)
    __shared__ __align__(16) __hip_bfloat16 lds_p[128][64];       // shared P tile 16KB (swizzled)
    float* lds_scale = reinterpret_cast<float*>(&lds_k[1][0][0]);
    int*   lds_flag  = reinterpret_cast<int*>(lds_scale + 128);   // [8]
    int b = blockIdx.y;
    int n0 = blockIdx.x * 128;
    int z = blockIdx.z;
    int t0 = z * tpb, t_end = t0 + tpb;
    __hip_bfloat16* opart = (z == 0) ? o0 : (z == 1) ? o1 : (z == 2) ? o2
                          : (z == 3) ? o3 : (z == 4) ? o4 : o5;
    int wave = threadIdx.x >> 6, lane = threadIdx.x & 63;
    int lr = lane & 15, lg = lane >> 4;
    int rowA = n0 + wave * 16 + lr;
    const size_t bN = (size_t)b * NN;

    f16x8 qh[8];
    #pragma unroll
    for (int ks = 0; ks < 8; ++ks) {
        int kk = ks * 32 + lg * 8;
        qh[ks] = ldh8(qt_hi + (bN + rowA) * CC + kk);
    }
    int hn[4], wn[4];
    #pragma unroll
    for (int r = 0; r < 4; ++r) {
        int n = n0 + wave * 16 + lg * 4 + r;
        hn[r] = n % HH;
        wn[r] = n / HH;
    }
    const float* rhq_b = rhq + (size_t)b * HH * NN;
    const float* rwq_b = rwq + (size_t)b * HH * NN;

    int nh = wave >> 2;                 // n-half
    int cq = wave & 3;                  // c-quarter
    f32x4 oacc[4][4] = {};              // [nf][cf]
    float mrun[4] = {-1e30f, -1e30f, -1e30f, -1e30f};
    float lrun[4] = {0.f, 0.f, 0.f, 0.f};   // per-lane partial (epilogue-reduced)

    int krin = lane >> 4, kch = lane & 15;
    auto STAGE_K = [&](int buf, int m0s, int k0) {
        #pragma unroll
        for (int j = 0; j < 2; ++j) {
            int lrow = wave * 8 + j * 4;
            int grow = lrow + krin;
            gload_lds16(kt + (bN + m0s + grow) * CC + k0 + ((kch ^ (grow & 7)) * 8),
                        &lds_k[buf][lrow][0]);
        }
    };
    int srl = lane >> 3;
    int sch = ((lane & 7) ^ srl) * 8;
    auto STAGE_V = [&](int half, int m0s) {
        #pragma unroll
        for (int j = 0; j < 2; ++j) {
            int lrow = half * 128 + wave * 16 + j * 8;
            int crow = lrow + srl;
            gload_lds16(vbuf + ((size_t)b * CC + crow) * NN + m0s + sch, &lds_v[lrow][0]);
        }
    };

    STAGE_K(0, t0 * 64, 0);
    __syncthreads();

    for (int t = t0; t < t_end; ++t) {
        int m0 = t * 64;
        float padd[4][4];
        #pragma unroll
        for (int mt = 0; mt < 4; ++mt) {
            int m = m0 + mt * 16 + lr;
            #pragma unroll
            for (int r = 0; r < 4; ++r)
                padd[mt][r] = rhq_b[(size_t)hn[r] * NN + m] + rwq_b[(size_t)wn[r] * NN + m];
        }
        f32x4 sacc[4] = {};
        #pragma unroll
        for (int s = 0; s < 2; ++s) {
            if (s == 0) {
                STAGE_K(1, m0, 128);
                STAGE_V(0, m0);
            } else {
                int mn = (t + 1 < t_end) ? (t + 1) * 64 : t0 * 64;
                STAGE_K(0, mn, 0);
                STAGE_V(1, m0);
            }
            __builtin_amdgcn_s_setprio(1);
            #pragma unroll
            for (int ks = 0; ks < 4; ++ks) {
                #pragma unroll
                for (int mt = 0; mt < 4; ++mt) {
                    int row = mt * 16 + lr;
                    int ch = ((ks * 4 + lg) ^ (lr & 7)) * 8;
                    f16x8 bh = *reinterpret_cast<const f16x8*>(&lds_k[s][row][ch]);
                    sacc[mt] = MFMAH(qh[s * 4 + ks], bh, sacc[mt]);
                }
            }
            __builtin_amdgcn_s_setprio(0);
            __syncthreads();
        }
        #pragma unroll
        for (int mt = 0; mt < 4; ++mt)
            #pragma unroll
            for (int r = 0; r < 4; ++r)
                sacc[mt][r] += padd[mt][r];
        bool lane_need = false;
        #pragma unroll
        for (int mt = 0; mt < 4; ++mt)
            #pragma unroll
            for (int r = 0; r < 4; ++r)
                lane_need |= (sacc[mt][r] > mrun[r] + 8.0f);
        bool wave_need = __any(lane_need);
        float scl_r[4] = {1.f, 1.f, 1.f, 1.f};
        if (wave_need) {
            #pragma unroll
            for (int r = 0; r < 4; ++r) {
                float smax = fmaxf(fmaxf(sacc[0][r], sacc[1][r]),
                                   fmaxf(sacc[2][r], sacc[3][r]));
                #pragma unroll
                for (int mk = 1; mk <= 8; mk <<= 1)
                    smax = fmaxf(smax, __shfl_xor(smax, mk));
                float mnew = fmaxf(mrun[r], smax);
                scl_r[r] = __expf(mrun[r] - mnew);
                mrun[r] = mnew;
                lrun[r] *= scl_r[r];
            }
        }
        #pragma unroll
        for (int r = 0; r < 4; ++r) {
            float rsum = 0.f;
            #pragma unroll
            for (int mt = 0; mt < 4; ++mt) {
                float p = __expf(sacc[mt][r] - mrun[r]);
                sacc[mt][r] = p;
                rsum += p;
            }
            lrun[r] += rsum;
        }
        #pragma unroll
        for (int mt = 0; mt < 4; ++mt) {
            #pragma unroll
            for (int r = 0; r < 4; ++r) {
                int prow = wave * 16 + lg * 4 + r;
                int pcol = mt * 16 + lr;
                int pcol_s = (((pcol >> 3) ^ (prow & 7)) << 3) | (pcol & 7);
                lds_p[prow][pcol_s] = __float2bfloat16(sacc[mt][r]);
            }
        }
        if (lr == 0) {
            #pragma unroll
            for (int r = 0; r < 4; ++r)
                lds_scale[wave * 16 + lg * 4 + r] = scl_r[r];
        }
        if (lane == 0) lds_flag[wave] = wave_need ? 1 : 0;
        __syncthreads();
        int4 f0 = *reinterpret_cast<const int4*>(&lds_flag[0]);
        int4 f1 = *reinterpret_cast<const int4*>(&lds_flag[4]);
        bool do_scale = (f0.x | f0.y | f0.z | f0.w | f1.x | f1.y | f1.z | f1.w) != 0;
        if (do_scale) {
            #pragma unroll
            for (int nf = 0; nf < 4; ++nf) {
                f32x4 s4 = *reinterpret_cast<const f32x4*>(&lds_scale[nh * 64 + nf * 16 + lg * 4]);
                #pragma unroll
                for (int cf = 0; cf < 4; ++cf)
                    oacc[nf][cf] *= s4;
            }
        }
        __builtin_amdgcn_s_setprio(1);
        #pragma unroll
        for (int ks2 = 0; ks2 < 2; ++ks2) {
            bf16x8 pa[4];
            #pragma unroll
            for (int nf = 0; nf < 4; ++nf) {
                int prow = nh * 64 + nf * 16 + lr;
                int pch = ((ks2 * 4 + lg) ^ (lr & 7)) * 8;
                pa[nf] = *reinterpret_cast<const bf16x8*>(&lds_p[prow][pch]);
            }
            #pragma unroll
            for (int cf = 0; cf < 4; ++cf) {
                int vrow = cq * 64 + cf * 16 + lr;
                int vch = ((ks2 * 4 + lg) ^ (lr & 7)) * 8;
                bf16x8 bv = *reinterpret_cast<const bf16x8*>(&lds_v[vrow][vch]);
                #pragma unroll
                for (int nf = 0; nf < 4; ++nf)
                    oacc[nf][cf] = MFMA(pa[nf], bv, oacc[nf][cf]);
            }
        }
        __builtin_amdgcn_s_setprio(0);
        __syncthreads();
    }
    #pragma unroll
    for (int r = 0; r < 4; ++r) {
        #pragma unroll
        for (int mk = 1; mk <= 8; mk <<= 1)
            lrun[r] += __shfl_xor(lrun[r], mk);
    }
    if (lr == 0) {
        #pragma unroll
        for (int r = 0; r < 4; ++r) {
            int n = n0 + wave * 16 + lg * 4 + r;
            ml[((size_t)z * BB + b) * NN + n] = make_float2(mrun[r], lrun[r]);
        }
    }
    #pragma unroll
    for (int nf = 0; nf < 4; ++nf) {
        int nbase = n0 + nh * 64 + nf * 16 + lg * 4;
        #pragma unroll
        for (int cf = 0; cf < 4; ++cf) {
            int c = cq * 64 + cf * 16 + lr;
            union { ushort4 u4; unsigned short us[4]; } pk;
            #pragma unroll
            for (int j = 0; j < 4; ++j) {
                __hip_bfloat16 hv = __float2bfloat16(oacc[nf][cf][j]);
                pk.us[j] = *reinterpret_cast<unsigned short*>(&hv);
            }
            *reinterpret_cast<ushort4*>(&opart[((size_t)b * CC + c) * NN + nbase]) = pk.u4;
        }
    }
}

// ---- combine: out[b][c][n] = sum_z o_z*exp(m_z-M) / sum_z l_z*exp(m_z-M) ----
__global__ __launch_bounds__(256) void k_combine(
        const __hip_bfloat16* __restrict__ o0, const __hip_bfloat16* __restrict__ o1,
        const __hip_bfloat16* __restrict__ o2, const __hip_bfloat16* __restrict__ o3,
        const __hip_bfloat16* __restrict__ o4, const __hip_bfloat16* __restrict__ o5,
        const float2* __restrict__ ml, int nsplit, float* __restrict__ out) {
    size_t idx = ((size_t)blockIdx.x * 256 + threadIdx.x) * 4;   // over B*CC*NN
    int n4 = (int)(idx % NN);
    int c  = (int)((idx / NN) % CC);
    int b  = (int)(idx / ((size_t)NN * CC));
    float M[4] = {-1e30f, -1e30f, -1e30f, -1e30f};
    for (int zz = 0; zz < nsplit; ++zz) {
        #pragma unroll
        for (int j = 0; j < 4; ++j)
            M[j] = fmaxf(M[j], ml[((size_t)zz * BB + b) * NN + n4 + j].x);
    }
    float num[4] = {}, den[4] = {};
    for (int zz = 0; zz < nsplit; ++zz) {
        const __hip_bfloat16* op = (zz == 0) ? o0 : (zz == 1) ? o1 : (zz == 2) ? o2
                                 : (zz == 3) ? o3 : (zz == 4) ? o4 : o5;
        ushort4 u = *reinterpret_cast<const ushort4*>(op + ((size_t)b * CC + c) * NN + n4);
        unsigned short us[4] = {u.x, u.y, u.z, u.w};
        #pragma unroll
        for (int j = 0; j < 4; ++j) {
            float2 v = ml[((size_t)zz * BB + b) * NN + n4 + j];
            float w = __expf(v.x - M[j]);
            num[j] += bf2f(us[j]) * w;
            den[j] += v.y * w;
        }
    }
    f32x4 o;
    #pragma unroll
    for (int j = 0; j < 4; ++j) o[j] = num[j] / den[j];
    *reinterpret_cast<f32x4*>(&out[idx]) = o;
}

extern "C" void kernel_launch(void* const* d_in, const int* in_sizes, int n_in,
                              void* d_out, int out_size, void* d_ws, size_t ws_size,
                              hipStream_t stream) {
    const float* x     = (const float*)d_in[0];
    const float* Wq    = (const float*)d_in[1];
    const float* bq    = (const float*)d_in[2];
    const float* Wk    = (const float*)d_in[3];
    const float* bk    = (const float*)d_in[4];
    const float* Wv    = (const float*)d_in[5];
    const float* bv    = (const float*)d_in[6];
    const float* rel_h = (const float*)d_in[7];
    const float* rel_w = (const float*)d_in[8];
    float* out = (float*)d_out;

    size_t off = 0;
    auto carve = [&](size_t bytes) {
        void* p = (char*)d_ws + off;
        off += (bytes + 255) & ~(size_t)255;
        return p;
    };
    const size_t sz_t = (size_t)BB * NN * CC * 2;   // one 2B plane = 18.87 MB
    _Float16* qt_hi  = (_Float16*)carve(sz_t);
    _Float16* kt     = (_Float16*)carve(sz_t);
    __hip_bfloat16* vbuf = (__hip_bfloat16*)carve(sz_t);
    _Float16* relhT = (_Float16*)carve((size_t)HH * CC * 2);
    _Float16* relwT = (_Float16*)carve((size_t)HH * CC * 2);
    _Float16* w     = (_Float16*)carve((size_t)3 * CC * CC * 2);
    float* rhq = (float*)carve((size_t)BB * HH * NN * 4);
    float* rwq = (float*)carve((size_t)BB * HH * NN * 4);
    float2* ml = (float2*)carve((size_t)6 * BB * NN * sizeof(float2));
    __hip_bfloat16* o0 = (__hip_bfloat16*)carve(sz_t);
    __hip_bfloat16* o1 = (__hip_bfloat16*)carve(sz_t);
    if (off > ws_size) return;   // base workspace too small -> visible failure

    __hip_bfloat16 *o2 = nullptr, *o3 = nullptr, *o4 = nullptr, *o5 = nullptr;
    int nsplit = 2;
    {
        size_t save = off;
        __hip_bfloat16* p2 = (__hip_bfloat16*)carve(sz_t);
        __hip_bfloat16* p3 = (__hip_bfloat16*)carve(sz_t);
        if (off <= ws_size) { nsplit = 4; o2 = p2; o3 = p3; }
        else { off = save; }
    }
    if (nsplit == 4) {
        size_t save = off;
        __hip_bfloat16* p4 = (__hip_bfloat16*)carve(sz_t);
        __hip_bfloat16* p5 = (__hip_bfloat16*)carve(sz_t);
        if (off <= ws_size) { nsplit = 6; o4 = p4; o5 = p5; }
        else { off = save; }
    }
    int tpb = 36 / nsplit;

    k_prep_w<<<dim3(3 * CC * CC / 256), 256, 0, stream>>>(Wq, Wk, Wv, w);
    k_prep_rel<<<dim3(HH * CC / 256), 256, 0, stream>>>(rel_h, rel_w, relhT, relwT);
    k_projqkv<<<dim3(NN / 32, BB), 256, 0, stream>>>(
        x, w, bq, bk, bv, relhT, relwT, qt_hi, kt, vbuf, rhq, rwq);
    k_attn<<<dim3(NN / 128, BB, nsplit), 512, 0, stream>>>(
        qt_hi, kt, rhq, rwq, vbuf, o0, o1, o2, o3, o4, o5, ml, tpb);
    k_combine<<<dim3((size_t)BB * CC * NN / 1024), 256, 0, stream>>>(
        o0, o1, o2, o3, o4, o5, ml, nsplit, out);
}

// Round 22
// 404.139 us; speedup vs baseline: 1.1001x; 1.1001x over previous
//
#include <hip/hip_runtime.h>
#include <hip/hip_bf16.h>

// MHSA: B=16, C=256, H=W=48, N=2304.  (R22 = R20 verbatim — best measured.)
// S[b,n,m] = q[b,:,n]·k[b,:,m] + rhq[b][n%48][m] + rwq[b][n/48][m]
// att = softmax_m(S); out[b,c,n] = sum_m v[b,c,m] att[n,m]
// Numerics: attn S q 1-pass f16, defer-max THR=8 (R17/18-proven, 0.0625).
// R21 lesson: setprio (no wave-diversity here) and nsplit=6 (per-block fixed
// costs > tail gain) BOTH regressed 404.6->444.6 — reverted.

#define BB 16
#define CC 256
#define HH 48
#define NN 2304

typedef float f32x4 __attribute__((ext_vector_type(4)));
typedef short bf16x8 __attribute__((ext_vector_type(8)));
typedef _Float16 f16x8 __attribute__((ext_vector_type(8)));

#define MFMA(a, b, c)  __builtin_amdgcn_mfma_f32_16x16x32_bf16((a), (b), (c), 0, 0, 0)
#define MFMAH(a, b, c) __builtin_amdgcn_mfma_f32_16x16x32_f16((a), (b), (c), 0, 0, 0)

__device__ inline bf16x8 ldg8(const __hip_bfloat16* p) {
    return *reinterpret_cast<const bf16x8*>(p);
}
__device__ inline f16x8 ldh8(const _Float16* p) {
    return *reinterpret_cast<const f16x8*>(p);
}
__device__ inline float bf2f(unsigned short v) {
    unsigned u = (unsigned)v << 16;
    float f;
    __builtin_memcpy(&f, &u, 4);
    return f;
}

typedef __attribute__((address_space(3))) unsigned int lds_uint;
typedef const __attribute__((address_space(1))) unsigned int gbl_uint;

__device__ inline void gload_lds16(const void* g, void* l) {
    __builtin_amdgcn_global_load_lds((gbl_uint*)g, (lds_uint*)l, 16, 0, 0);
}

// ---- prep: W -> single f16 plane ([3][256][256]) ----
__global__ __launch_bounds__(256) void k_prep_w(const float* __restrict__ Wq,
        const float* __restrict__ Wk, const float* __restrict__ Wv,
        _Float16* __restrict__ w) {
    int i = blockIdx.x * 256 + threadIdx.x;         // < 3*65536
    int m = i >> 16, j = i & 65535;
    const float* W = (m == 0) ? Wq : ((m == 1) ? Wk : Wv);
    w[i] = (_Float16)W[j];
}

// ---- prep: relhT[h][c] = rel_h[c][h] etc, f16 ----
__global__ __launch_bounds__(256) void k_prep_rel(const float* __restrict__ rel_h,
        const float* __restrict__ rel_w,
        _Float16* __restrict__ relhT, _Float16* __restrict__ relwT) {
    int i = blockIdx.x * 256 + threadIdx.x;         // < 48*256
    int h = i >> 8, c = i & 255;
    relhT[i] = (_Float16)rel_h[c * HH + h];
    relwT[i] = (_Float16)rel_w[c * HH + h];
}

// ---- unified QKV projection + fused pos rank-split (R20) ----
// grid (72, 16); block = 32 n-rows, 4 waves (o-slice 64 each).
__global__ __launch_bounds__(256) void k_projqkv(
        const float* __restrict__ x,
        const _Float16* __restrict__ w,
        const float* __restrict__ bq, const float* __restrict__ bk, const float* __restrict__ bv,
        const _Float16* __restrict__ relhT, const _Float16* __restrict__ relwT,
        _Float16* __restrict__ qt_hi, _Float16* __restrict__ kt,
        __hip_bfloat16* __restrict__ vbuf,
        float* __restrict__ rhq, float* __restrict__ rwq) {
    __shared__ float xf[32][257];                          // 32.9KB; reused: qlds, v-repack
    __shared__ __align__(16) _Float16 lds_a[2][32][256];   // [hi/lo][row][c] 32KB swizzled
    _Float16* qlds = reinterpret_cast<_Float16*>(&xf[0][0]);        // [2][32][256] swizzled
    __hip_bfloat16* vt = reinterpret_cast<__hip_bfloat16*>(&xf[0][0]); // [256][40] padded
    int b = blockIdx.y;
    int n0 = blockIdx.x * 32;
    int t = threadIdx.x;
    int wave = t >> 6, lane = t & 63;
    int lr = lane & 15, lg = lane >> 4;
    int o0 = wave * 64;
    const size_t bN = (size_t)b * NN;

    // load x (coalesced 128B per c-row) into f32 tile
    {
        int nj = t & 31, cg = t >> 5;
        #pragma unroll
        for (int it = 0; it < 32; ++it) {
            int c = it * 8 + cg;
            xf[nj][c] = x[((size_t)b * CC + c) * NN + n0 + nj];
        }
    }
    __syncthreads();
    // split to f16 hi/lo, write swizzled
    {
        int r = t & 31, cg = t >> 5;
        #pragma unroll
        for (int i = 0; i < 32; ++i) {
            int c = cg + 8 * i;
            float v = xf[r][c];
            _Float16 h = (_Float16)v;
            int pc = (((c >> 3) ^ (r & 7)) << 3) | (c & 7);
            lds_a[0][r][pc] = h;
            lds_a[1][r][pc] = (_Float16)(v - (float)h);
        }
    }
    __syncthreads();   // xf reads complete -> safe to overwrite as qlds

    // ---- q-GEMM (pj=0, 2-pass) ----
    {
        const _Float16* wp = w;
        f32x4 acc[2][4] = {};
        #pragma unroll
        for (int ks = 0; ks < 8; ++ks) {
            int kk = ks * 32 + lg * 8;
            f16x8 ah[2], al[2];
            #pragma unroll
            for (int nt = 0; nt < 2; ++nt) {
                int row = nt * 16 + lr;
                int ch = ((ks * 4 + lg) ^ (lr & 7)) * 8;
                ah[nt] = *reinterpret_cast<const f16x8*>(&lds_a[0][row][ch]);
                al[nt] = *reinterpret_cast<const f16x8*>(&lds_a[1][row][ch]);
            }
            #pragma unroll
            for (int ot = 0; ot < 4; ++ot) {
                int rowB = o0 + ot * 16 + lr;
                f16x8 bh = ldh8(wp + rowB * CC + kk);
                #pragma unroll
                for (int nt = 0; nt < 2; ++nt) {
                    acc[nt][ot] = MFMAH(ah[nt], bh, acc[nt][ot]);
                    acc[nt][ot] = MFMAH(al[nt], bh, acc[nt][ot]);
                }
            }
        }
        #pragma unroll
        for (int ot = 0; ot < 4; ++ot) {
            int o = o0 + ot * 16 + lr;
            float bb = bq[o];
            #pragma unroll
            for (int nt = 0; nt < 2; ++nt) {
                #pragma unroll
                for (int r = 0; r < 4; ++r) {
                    int nl = nt * 16 + lg * 4 + r;
                    float y = acc[nt][ot][r] + bb;
                    _Float16 h = (_Float16)y;
                    _Float16 lo = (_Float16)(y - (float)h);
                    qt_hi[(bN + n0 + nl) * CC + o] = h;
                    int pc = (((o >> 3) ^ (nl & 7)) << 3) | (o & 7);
                    qlds[nl * 256 + pc] = h;
                    qlds[8192 + nl * 256 + pc] = lo;
                }
            }
        }
    }
    __syncthreads();   // qlds complete (all waves)

    // ---- fused pos rank-split (bit-identical to old k_posq) ----
    // wave 0,1 -> rh (m-tile 0,1); wave 2,3 -> rw (m-tile 0,1)
    {
        int rel_sel = wave >> 1, mtile = wave & 1;
        const _Float16* rel = rel_sel ? relwT : relhT;
        float* rout = rel_sel ? rwq : rhq;
        int brow = mtile * 16 + lr;
        f32x4 pacc[3] = {};
        #pragma unroll
        for (int ks = 0; ks < 8; ++ks) {
            int kk = ks * 32 + lg * 8;
            int bch = ((ks * 4 + lg) ^ (brow & 7)) * 8;
            f16x8 bh = *reinterpret_cast<const f16x8*>(&qlds[brow * 256 + bch]);
            f16x8 bl = *reinterpret_cast<const f16x8*>(&qlds[8192 + brow * 256 + bch]);
            #pragma unroll
            for (int ht = 0; ht < 3; ++ht) {
                f16x8 a = ldh8(rel + (ht * 16 + lr) * CC + kk);
                pacc[ht] = MFMAH(a, bh, pacc[ht]);
                pacc[ht] = MFMAH(a, bl, pacc[ht]);
            }
        }
        #pragma unroll
        for (int ht = 0; ht < 3; ++ht) {
            #pragma unroll
            for (int r = 0; r < 4; ++r) {
                int h = ht * 16 + lg * 4 + r;
                int m = n0 + mtile * 16 + lr;
                rout[((size_t)b * HH + h) * NN + m] = pacc[ht][r];
            }
        }
    }

    // ---- k-GEMM (pj=1, 2-pass) ----
    {
        const _Float16* wp = w + 65536;
        f32x4 acc[2][4] = {};
        #pragma unroll
        for (int ks = 0; ks < 8; ++ks) {
            int kk = ks * 32 + lg * 8;
            f16x8 ah[2], al[2];
            #pragma unroll
            for (int nt = 0; nt < 2; ++nt) {
                int row = nt * 16 + lr;
                int ch = ((ks * 4 + lg) ^ (lr & 7)) * 8;
                ah[nt] = *reinterpret_cast<const f16x8*>(&lds_a[0][row][ch]);
                al[nt] = *reinterpret_cast<const f16x8*>(&lds_a[1][row][ch]);
            }
            #pragma unroll
            for (int ot = 0; ot < 4; ++ot) {
                int rowB = o0 + ot * 16 + lr;
                f16x8 bh = ldh8(wp + rowB * CC + kk);
                #pragma unroll
                for (int nt = 0; nt < 2; ++nt) {
                    acc[nt][ot] = MFMAH(ah[nt], bh, acc[nt][ot]);
                    acc[nt][ot] = MFMAH(al[nt], bh, acc[nt][ot]);
                }
            }
        }
        #pragma unroll
        for (int ot = 0; ot < 4; ++ot) {
            int o = o0 + ot * 16 + lr;
            float bb = bk[o];
            #pragma unroll
            for (int nt = 0; nt < 2; ++nt) {
                #pragma unroll
                for (int r = 0; r < 4; ++r) {
                    int nl = nt * 16 + lg * 4 + r;
                    kt[(bN + n0 + nl) * CC + o] = (_Float16)(acc[nt][ot][r] + bb);
                }
            }
        }
    }

    // ---- v-GEMM (pj=2, 1-pass) + full-line store via LDS repack ----
    {
        const _Float16* wp = w + 2 * 65536;
        f32x4 acc[2][4] = {};
        #pragma unroll
        for (int ks = 0; ks < 8; ++ks) {
            int kk = ks * 32 + lg * 8;
            f16x8 ah[2];
            #pragma unroll
            for (int nt = 0; nt < 2; ++nt) {
                int row = nt * 16 + lr;
                int ch = ((ks * 4 + lg) ^ (lr & 7)) * 8;
                ah[nt] = *reinterpret_cast<const f16x8*>(&lds_a[0][row][ch]);
            }
            #pragma unroll
            for (int ot = 0; ot < 4; ++ot) {
                int rowB = o0 + ot * 16 + lr;
                f16x8 bh = ldh8(wp + rowB * CC + kk);
                #pragma unroll
                for (int nt = 0; nt < 2; ++nt)
                    acc[nt][ot] = MFMAH(ah[nt], bh, acc[nt][ot]);
            }
        }
        __syncthreads();   // all waves past pos-phase reads of qlds (xf reuse)
        #pragma unroll
        for (int ot = 0; ot < 4; ++ot) {
            int o = o0 + ot * 16 + lr;
            float bb = bv[o];
            #pragma unroll
            for (int nt = 0; nt < 2; ++nt) {
                #pragma unroll
                for (int r = 0; r < 4; ++r) {
                    int nl = nt * 16 + lg * 4 + r;
                    vt[o * 40 + nl] = __float2bfloat16(acc[nt][ot][r] + bb);
                }
            }
        }
        __syncthreads();
        // thread t stores c-row t: 64B = one full cache line
        #pragma unroll
        for (int j = 0; j < 4; ++j) {
            bf16x8 vv = *reinterpret_cast<const bf16x8*>(&vt[t * 40 + j * 8]);
            *reinterpret_cast<bf16x8*>(&vbuf[((size_t)b * CC + t) * NN + n0 + j * 8]) = vv;
        }
    }
}

// ---- flash attention, split-KV, shuffle-free steady-state softmax (R18) ----
__global__ __launch_bounds__(512, 2) void k_attn(
        const _Float16* __restrict__ qt_hi,
        const _Float16* __restrict__ kt,
        const float* __restrict__ rhq, const float* __restrict__ rwq,
        const __hip_bfloat16* __restrict__ vbuf,
        __hip_bfloat16* __restrict__ o0, __hip_bfloat16* __restrict__ o1,
        __hip_bfloat16* __restrict__ o2, __hip_bfloat16* __restrict__ o3,
        float2* __restrict__ ml, int tpb) {
    __shared__ __align__(16) _Float16 lds_k[2][64][128];          // [slice][row][k] 32KB
    __shared__ __align__(16) __hip_bfloat16 lds_v[256][64];       // [c][m] 32KB (swizzled)
    __shared__ __align__(16) __hip_bfloat16 lds_p[128][64];       // shared P tile 16KB (swizzled)
    float* lds_scale = reinterpret_cast<float*>(&lds_k[1][0][0]);
    int*   lds_flag  = reinterpret_cast<int*>(lds_scale + 128);   // [8]
    int b = blockIdx.y;
    int n0 = blockIdx.x * 128;
    int z = blockIdx.z;
    int t0 = z * tpb, t_end = t0 + tpb;
    __hip_bfloat16* opart = (z == 0) ? o0 : (z == 1) ? o1 : (z == 2) ? o2 : o3;
    int wave = threadIdx.x >> 6, lane = threadIdx.x & 63;
    int lr = lane & 15, lg = lane >> 4;
    int rowA = n0 + wave * 16 + lr;
    const size_t bN = (size_t)b * NN;

    f16x8 qh[8];
    #pragma unroll
    for (int ks = 0; ks < 8; ++ks) {
        int kk = ks * 32 + lg * 8;
        qh[ks] = ldh8(qt_hi + (bN + rowA) * CC + kk);
    }
    int hn[4], wn[4];
    #pragma unroll
    for (int r = 0; r < 4; ++r) {
        int n = n0 + wave * 16 + lg * 4 + r;
        hn[r] = n % HH;
        wn[r] = n / HH;
    }
    const float* rhq_b = rhq + (size_t)b * HH * NN;
    const float* rwq_b = rwq + (size_t)b * HH * NN;

    int nh = wave >> 2;                 // n-half
    int cq = wave & 3;                  // c-quarter
    f32x4 oacc[4][4] = {};              // [nf][cf]
    float mrun[4] = {-1e30f, -1e30f, -1e30f, -1e30f};
    float lrun[4] = {0.f, 0.f, 0.f, 0.f};   // per-lane partial (epilogue-reduced)

    int krin = lane >> 4, kch = lane & 15;
    auto STAGE_K = [&](int buf, int m0s, int k0) {
        #pragma unroll
        for (int j = 0; j < 2; ++j) {
            int lrow = wave * 8 + j * 4;
            int grow = lrow + krin;
            gload_lds16(kt + (bN + m0s + grow) * CC + k0 + ((kch ^ (grow & 7)) * 8),
                        &lds_k[buf][lrow][0]);
        }
    };
    int srl = lane >> 3;
    int sch = ((lane & 7) ^ srl) * 8;
    auto STAGE_V = [&](int half, int m0s) {
        #pragma unroll
        for (int j = 0; j < 2; ++j) {
            int lrow = half * 128 + wave * 16 + j * 8;
            int crow = lrow + srl;
            gload_lds16(vbuf + ((size_t)b * CC + crow) * NN + m0s + sch, &lds_v[lrow][0]);
        }
    };

    STAGE_K(0, t0 * 64, 0);
    __syncthreads();

    for (int t = t0; t < t_end; ++t) {
        int m0 = t * 64;
        float padd[4][4];
        #pragma unroll
        for (int mt = 0; mt < 4; ++mt) {
            int m = m0 + mt * 16 + lr;
            #pragma unroll
            for (int r = 0; r < 4; ++r)
                padd[mt][r] = rhq_b[(size_t)hn[r] * NN + m] + rwq_b[(size_t)wn[r] * NN + m];
        }
        f32x4 sacc[4] = {};
        #pragma unroll
        for (int s = 0; s < 2; ++s) {
            if (s == 0) {
                STAGE_K(1, m0, 128);
                STAGE_V(0, m0);
            } else {
                int mn = (t + 1 < t_end) ? (t + 1) * 64 : t0 * 64;
                STAGE_K(0, mn, 0);
                STAGE_V(1, m0);
            }
            #pragma unroll
            for (int ks = 0; ks < 4; ++ks) {
                #pragma unroll
                for (int mt = 0; mt < 4; ++mt) {
                    int row = mt * 16 + lr;
                    int ch = ((ks * 4 + lg) ^ (lr & 7)) * 8;
                    f16x8 bh = *reinterpret_cast<const f16x8*>(&lds_k[s][row][ch]);
                    sacc[mt] = MFMAH(qh[s * 4 + ks], bh, sacc[mt]);
                }
            }
            __syncthreads();
        }
        #pragma unroll
        for (int mt = 0; mt < 4; ++mt)
            #pragma unroll
            for (int r = 0; r < 4; ++r)
                sacc[mt][r] += padd[mt][r];
        bool lane_need = false;
        #pragma unroll
        for (int mt = 0; mt < 4; ++mt)
            #pragma unroll
            for (int r = 0; r < 4; ++r)
                lane_need |= (sacc[mt][r] > mrun[r] + 8.0f);
        bool wave_need = __any(lane_need);
        float scl_r[4] = {1.f, 1.f, 1.f, 1.f};
        if (wave_need) {
            #pragma unroll
            for (int r = 0; r < 4; ++r) {
                float smax = fmaxf(fmaxf(sacc[0][r], sacc[1][r]),
                                   fmaxf(sacc[2][r], sacc[3][r]));
                #pragma unroll
                for (int mk = 1; mk <= 8; mk <<= 1)
                    smax = fmaxf(smax, __shfl_xor(smax, mk));
                float mnew = fmaxf(mrun[r], smax);
                scl_r[r] = __expf(mrun[r] - mnew);
                mrun[r] = mnew;
                lrun[r] *= scl_r[r];
            }
        }
        #pragma unroll
        for (int r = 0; r < 4; ++r) {
            float rsum = 0.f;
            #pragma unroll
            for (int mt = 0; mt < 4; ++mt) {
                float p = __expf(sacc[mt][r] - mrun[r]);
                sacc[mt][r] = p;
                rsum += p;
            }
            lrun[r] += rsum;
        }
        #pragma unroll
        for (int mt = 0; mt < 4; ++mt) {
            #pragma unroll
            for (int r = 0; r < 4; ++r) {
                int prow = wave * 16 + lg * 4 + r;
                int pcol = mt * 16 + lr;
                int pcol_s = (((pcol >> 3) ^ (prow & 7)) << 3) | (pcol & 7);
                lds_p[prow][pcol_s] = __float2bfloat16(sacc[mt][r]);
            }
        }
        if (lr == 0) {
            #pragma unroll
            for (int r = 0; r < 4; ++r)
                lds_scale[wave * 16 + lg * 4 + r] = scl_r[r];
        }
        if (lane == 0) lds_flag[wave] = wave_need ? 1 : 0;
        __syncthreads();
        int4 f0 = *reinterpret_cast<const int4*>(&lds_flag[0]);
        int4 f1 = *reinterpret_cast<const int4*>(&lds_flag[4]);
        bool do_scale = (f0.x | f0.y | f0.z | f0.w | f1.x | f1.y | f1.z | f1.w) != 0;
        if (do_scale) {
            #pragma unroll
            for (int nf = 0; nf < 4; ++nf) {
                f32x4 s4 = *reinterpret_cast<const f32x4*>(&lds_scale[nh * 64 + nf * 16 + lg * 4]);
                #pragma unroll
                for (int cf = 0; cf < 4; ++cf)
                    oacc[nf][cf] *= s4;
            }
        }
        #pragma unroll
        for (int ks2 = 0; ks2 < 2; ++ks2) {
            bf16x8 pa[4];
            #pragma unroll
            for (int nf = 0; nf < 4; ++nf) {
                int prow = nh * 64 + nf * 16 + lr;
                int pch = ((ks2 * 4 + lg) ^ (lr & 7)) * 8;
                pa[nf] = *reinterpret_cast<const bf16x8*>(&lds_p[prow][pch]);
            }
            #pragma unroll
            for (int cf = 0; cf < 4; ++cf) {
                int vrow = cq * 64 + cf * 16 + lr;
                int vch = ((ks2 * 4 + lg) ^ (lr & 7)) * 8;
                bf16x8 bv = *reinterpret_cast<const bf16x8*>(&lds_v[vrow][vch]);
                #pragma unroll
                for (int nf = 0; nf < 4; ++nf)
                    oacc[nf][cf] = MFMA(pa[nf], bv, oacc[nf][cf]);
            }
        }
        __syncthreads();
    }
    #pragma unroll
    for (int r = 0; r < 4; ++r) {
        #pragma unroll
        for (int mk = 1; mk <= 8; mk <<= 1)
            lrun[r] += __shfl_xor(lrun[r], mk);
    }
    if (lr == 0) {
        #pragma unroll
        for (int r = 0; r < 4; ++r) {
            int n = n0 + wave * 16 + lg * 4 + r;
            ml[((size_t)z * BB + b) * NN + n] = make_float2(mrun[r], lrun[r]);
        }
    }
    #pragma unroll
    for (int nf = 0; nf < 4; ++nf) {
        int nbase = n0 + nh * 64 + nf * 16 + lg * 4;
        #pragma unroll
        for (int cf = 0; cf < 4; ++cf) {
            int c = cq * 64 + cf * 16 + lr;
            union { ushort4 u4; unsigned short us[4]; } pk;
            #pragma unroll
            for (int j = 0; j < 4; ++j) {
                __hip_bfloat16 hv = __float2bfloat16(oacc[nf][cf][j]);
                pk.us[j] = *reinterpret_cast<unsigned short*>(&hv);
            }
            *reinterpret_cast<ushort4*>(&opart[((size_t)b * CC + c) * NN + nbase]) = pk.u4;
        }
    }
}

// ---- combine: out[b][c][n] = sum_z o_z*exp(m_z-M) / sum_z l_z*exp(m_z-M) ----
__global__ __launch_bounds__(256) void k_combine(
        const __hip_bfloat16* __restrict__ o0, const __hip_bfloat16* __restrict__ o1,
        const __hip_bfloat16* __restrict__ o2, const __hip_bfloat16* __restrict__ o3,
        const float2* __restrict__ ml, int nsplit, float* __restrict__ out) {
    size_t idx = ((size_t)blockIdx.x * 256 + threadIdx.x) * 4;   // over B*CC*NN
    int n4 = (int)(idx % NN);
    int c  = (int)((idx / NN) % CC);
    int b  = (int)(idx / ((size_t)NN * CC));
    float M[4] = {-1e30f, -1e30f, -1e30f, -1e30f};
    for (int zz = 0; zz < nsplit; ++zz) {
        #pragma unroll
        for (int j = 0; j < 4; ++j)
            M[j] = fmaxf(M[j], ml[((size_t)zz * BB + b) * NN + n4 + j].x);
    }
    float num[4] = {}, den[4] = {};
    for (int zz = 0; zz < nsplit; ++zz) {
        const __hip_bfloat16* op = (zz == 0) ? o0 : (zz == 1) ? o1 : (zz == 2) ? o2 : o3;
        ushort4 u = *reinterpret_cast<const ushort4*>(op + ((size_t)b * CC + c) * NN + n4);
        unsigned short us[4] = {u.x, u.y, u.z, u.w};
        #pragma unroll
        for (int j = 0; j < 4; ++j) {
            float2 v = ml[((size_t)zz * BB + b) * NN + n4 + j];
            float w = __expf(v.x - M[j]);
            num[j] += bf2f(us[j]) * w;
            den[j] += v.y * w;
        }
    }
    f32x4 o;
    #pragma unroll
    for (int j = 0; j < 4; ++j) o[j] = num[j] / den[j];
    *reinterpret_cast<f32x4*>(&out[idx]) = o;
}

extern "C" void kernel_launch(void* const* d_in, const int* in_sizes, int n_in,
                              void* d_out, int out_size, void* d_ws, size_t ws_size,
                              hipStream_t stream) {
    const float* x     = (const float*)d_in[0];
    const float* Wq    = (const float*)d_in[1];
    const float* bq    = (const float*)d_in[2];
    const float* Wk    = (const float*)d_in[3];
    const float* bk    = (const float*)d_in[4];
    const float* Wv    = (const float*)d_in[5];
    const float* bv    = (const float*)d_in[6];
    const float* rel_h = (const float*)d_in[7];
    const float* rel_w = (const float*)d_in[8];
    float* out = (float*)d_out;

    size_t off = 0;
    auto carve = [&](size_t bytes) {
        void* p = (char*)d_ws + off;
        off += (bytes + 255) & ~(size_t)255;
        return p;
    };
    const size_t sz_t = (size_t)BB * NN * CC * 2;   // one 2B plane = 18.87 MB
    _Float16* qt_hi  = (_Float16*)carve(sz_t);
    _Float16* kt     = (_Float16*)carve(sz_t);
    __hip_bfloat16* vbuf = (__hip_bfloat16*)carve(sz_t);
    _Float16* relhT = (_Float16*)carve((size_t)HH * CC * 2);
    _Float16* relwT = (_Float16*)carve((size_t)HH * CC * 2);
    _Float16* w     = (_Float16*)carve((size_t)3 * CC * CC * 2);
    float* rhq = (float*)carve((size_t)BB * HH * NN * 4);
    float* rwq = (float*)carve((size_t)BB * HH * NN * 4);
    float2* ml = (float2*)carve((size_t)4 * BB * NN * sizeof(float2));
    __hip_bfloat16* o0 = (__hip_bfloat16*)carve(sz_t);
    __hip_bfloat16* o1 = (__hip_bfloat16*)carve(sz_t);
    if (off > ws_size) return;   // base workspace too small -> visible failure

    __hip_bfloat16* o2 = nullptr;
    __hip_bfloat16* o3 = nullptr;
    int nsplit = 2;
    {
        size_t save = off;
        __hip_bfloat16* p2 = (__hip_bfloat16*)carve(sz_t);
        __hip_bfloat16* p3 = (__hip_bfloat16*)carve(sz_t);
        if (off <= ws_size) { nsplit = 4; o2 = p2; o3 = p3; }
        else { off = save; }
    }
    int tpb = 36 / nsplit;

    k_prep_w<<<dim3(3 * CC * CC / 256), 256, 0, stream>>>(Wq, Wk, Wv, w);
    k_prep_rel<<<dim3(HH * CC / 256), 256, 0, stream>>>(rel_h, rel_w, relhT, relwT);
    k_projqkv<<<dim3(NN / 32, BB), 256, 0, stream>>>(
        x, w, bq, bk, bv, relhT, relwT, qt_hi, kt, vbuf, rhq, rwq);
    k_attn<<<dim3(NN / 128, BB, nsplit), 512, 0, stream>>>(
        qt_hi, kt, rhq, rwq, vbuf, o0, o1, o2, o3, ml, tpb);
    k_combine<<<dim3((size_t)BB * CC * NN / 1024), 256, 0, stream>>>(
        o0, o1, o2, o3, ml, nsplit, out);
}